// Round 7
// baseline (177.492 us; speedup 1.0000x reference)
//
#include <hip/hip_runtime.h>
#include <math.h>

#define B_ 32
#define H_ 112
#define W_ 112
#define C_ 192
#define C4 (C_/4)              // 48
#define R_ 7                   // output rows per block
#define TPI (H_/R_)            // 16 tiles per image
#define NBLK (B_*TPI)          // 512 blocks = exactly 2 per CU
#define HALO 3
#define SR (R_ + 2*HALO)       // 13 staged (avg,max) rows
#define SWP 120                // padded LDS width (118 used)
#define NT_ 1024
#define NSLOT (SR*W_)          // 1456 staged positions
#define NITER ((NSLOT + 63)/64) // 23: compile-time trip count

typedef float nf4 __attribute__((ext_vector_type(4)));

// Fused 3-phase kernel. R7 change vs R6: phase 1 is BRANCH-FREE with a
// static 23-iteration unrolled loop -> the scheduler can hoist the next
// iteration's global loads above the current iteration's dependent shuffle
// chain (R6 compiled to VGPR=20 = exactly one iteration in flight -> 3.4 TB/s).
__global__ __launch_bounds__(NT_, 8) void fused_kernel(const float* __restrict__ x,
                                                       const float* __restrict__ w,
                                                       float* __restrict__ out) {
    __shared__ float2 sm[SR][SWP];    // 12.5 KB
    __shared__ float  sw[98];
    __shared__ float  satt[R_ * W_];  // 3.1 KB

    const int tid = threadIdx.x;
    // XCD swizzle (512 % 8 == 0 -> bijective): each XCD owns 64 contiguous tiles.
    const int bid = ((int)blockIdx.x & 7) * (NBLK / 8) + ((int)blockIdx.x >> 3);
    const int b   = bid / TPI;
    const int t   = bid - b * TPI;
    const int y0  = t * R_;

    if (tid < 98) sw[tid] = w[tid];
    for (int i = tid; i < SR * SWP; i += NT_)
        ((float2*)sm)[i] = make_float2(0.0f, 0.0f);   // zeroes the column halo
    __syncthreads();

    // ---- phase 1: channel mean/max, branch-free, fully unrolled ----
    const int g   = tid >> 4;          // 16-lane group id, 0..63
    const int sub = tid & 15;
    const float* ximg = x + (size_t)(b * H_) * W_ * C_;
    #pragma unroll
    for (int j = 0; j < NITER; ++j) {
        int ps = j * 64 + g;
        ps = (ps < NSLOT) ? ps : (NSLOT - 1);        // clamp: uniform redundant work
        const int r  = ps / W_;
        const int cl = ps - r * W_;
        const int yy = y0 + r - HALO;
        const int yc = min(max(yy, 0), H_ - 1);      // clamped row: always-safe load
        const float zf = (yy == yc) ? 1.0f : 0.0f;   // 0 outside the image
        const nf4* xp = (const nf4*)(ximg + ((size_t)yc * W_ + cl) * C_);
        nf4 a0 = xp[sub];
        nf4 a1 = xp[sub + 16];
        nf4 a2 = xp[sub + 32];
        float s = ((a0[0]+a0[1]) + (a0[2]+a0[3]))
                + ((a1[0]+a1[1]) + (a1[2]+a1[3]))
                + ((a2[0]+a2[1]) + (a2[2]+a2[3]));
        float m0 = fmaxf(fmaxf(a0[0], a0[1]), fmaxf(a0[2], a0[3]));
        float m1 = fmaxf(fmaxf(a1[0], a1[1]), fmaxf(a1[2], a1[3]));
        float m2 = fmaxf(fmaxf(a2[0], a2[1]), fmaxf(a2[2], a2[3]));
        float m  = fmaxf(m0, fmaxf(m1, m2));
        #pragma unroll
        for (int off = 8; off > 0; off >>= 1) {
            s += __shfl_xor(s, off);
            m = fmaxf(m, __shfl_xor(m, off));
        }
        if (sub == 0)
            sm[r][HALO + cl] = make_float2(s * (zf / (float)C_), m * zf);
    }
    __syncthreads();

    // ---- phase 2: 7x7 conv + sigmoid (halo zeroed, no bounds checks) ----
    if (tid < R_ * W_) {
        const int r  = tid / W_;
        const int cl = tid - r * W_;
        float acc = 0.0f;
        #pragma unroll
        for (int ky = 0; ky < 7; ++ky) {
            #pragma unroll
            for (int kx = 0; kx < 7; ++kx) {
                float2 am = sm[r + ky][cl + kx];
                acc = fmaf(am.x, sw[(ky * 7 + kx) * 2 + 0], acc);
                acc = fmaf(am.y, sw[(ky * 7 + kx) * 2 + 1], acc);
            }
        }
        satt[tid] = 1.0f / (1.0f + __expf(-acc));
    }
    __syncthreads();

    // ---- phase 3: out = x * att over the tile's 7 rows ----
    const size_t base4 = (size_t)(b * H_ + y0) * W_ * C4;
    const nf4* xr   = (const nf4*)x + base4;
    nf4*       orow = (nf4*)out + base4;
    #pragma unroll 4
    for (int f = tid; f < R_ * W_ * C4; f += NT_) {
        nf4 v = xr[f];                              // regular load: want cache hit
        v = v * satt[f / C4];
        __builtin_nontemporal_store(v, &orow[f]);   // dead data: don't pollute L3
    }
}

extern "C" void kernel_launch(void* const* d_in, const int* in_sizes, int n_in,
                              void* d_out, int out_size, void* d_ws, size_t ws_size,
                              hipStream_t stream) {
    const float* x = (const float*)d_in[0];
    const float* w = (const float*)d_in[1];
    float* out = (float*)d_out;
    fused_kernel<<<NBLK, NT_, 0, stream>>>(x, w, out);
}